// Round 3
// baseline (5258.668 us; speedup 1.0000x reference)
//
#include <hip/hip_runtime.h>
#include <hip/hip_bf16.h>

// ---------------------------------------------------------------------------
// LSTM-CRF forward on MI355X.
// R3: fence-free slice-parallel LSTM. h exchanged via relaxed agent-scope
// atomic dwords (write-through to coherence point); producer orders data
// before flag with the __syncthreads() vmcnt(0) drain; consumers poll the
// flag relaxed and load A fragments straight into registers (no LDS A, no
// acquire fence -> no per-step L2 invalidation; Gin stays cached).
// ---------------------------------------------------------------------------

#define Bv 32
#define Tv 256
#define Ev 300
#define HDv 256
#define Kv 64
#define MROWS (Bv * Tv)          // 8192
#define K0PAD 320                // 301 padded to mult of 32
#define GATES 1024               // 4*HD
#define NSLICE 16                // j-slices per dir
#define JS 16                    // j per slice
#define WFRAG_PER_DS (4 * 8 * 64 * 8)   // shorts per (dir,slice) weight block

typedef __bf16 v8bf __attribute__((ext_vector_type(8)));
typedef float  v4f  __attribute__((ext_vector_type(4)));

__device__ __forceinline__ unsigned short f2bf(float f) {
    unsigned u = __float_as_uint(f);
    unsigned r = (u + 0x7fffu + ((u >> 16) & 1u)) >> 16;
    return (unsigned short)r;
}
__device__ __forceinline__ float sigf(float x) { return 1.0f / (1.0f + __expf(-x)); }
__device__ __forceinline__ float tanhf2(float x) {
    x = fminf(15.f, fmaxf(-15.f, x));
    float e = __expf(2.f * x);
    return (e - 1.f) / (e + 1.f);
}

// ---------------- prep kernels ----------------

__global__ void conv_weights(const float* w0f, const float* w0b,
                             const float* w1f, const float* w1b,
                             const float* outw,
                             unsigned short* dW0, unsigned short* dW1,
                             unsigned short* dOW) {
    int z = blockIdx.z;
    const float* src; unsigned short* dst; int rows, kin, kout;
    if (z == 0)      { src = w0f;  dst = dW0;                rows = 1024; kin = 301; kout = K0PAD; }
    else if (z == 1) { src = w0b;  dst = dW0 + 1024 * K0PAD; rows = 1024; kin = 301; kout = K0PAD; }
    else if (z == 2) { src = w1f;  dst = dW1;                rows = 1024; kin = 512; kout = 512; }
    else if (z == 3) { src = w1b;  dst = dW1 + 1024 * 512;   rows = 1024; kin = 512; kout = 512; }
    else             { src = outw; dst = dOW;                rows = 64;   kin = 512; kout = 512; }
    int idx = blockIdx.x * 256 + threadIdx.x;
    if (idx >= rows * kout) return;
    int j = idx / kout, k = idx - j * kout;
    dst[idx] = (k < kin) ? f2bf(src[j * kin + k]) : (unsigned short)0;
}

// Whh [1024,256] fp32 -> bf16 MFMA B-fragment order:
// per (layer*2+dir) z: [slice(16)][gate(4)][kt(8)][lane(64)][e(8)]
// value = Whh[gate*256 + slice*16 + (lane&15)][kt*32 + (lane>>4)*8 + e]
__global__ void whh_frag(const float* h0f, const float* h0b,
                         const float* h1f, const float* h1b, unsigned short* Wfrag) {
    int z = blockIdx.z;
    const float* src = (z == 0) ? h0f : (z == 1) ? h0b : (z == 2) ? h1f : h1b;
    unsigned short* dst = Wfrag + (size_t)z * (NSLICE * WFRAG_PER_DS);
    int idx = blockIdx.x * 256 + threadIdx.x;          // 0..262143
    int e = idx & 7, ln = (idx >> 3) & 63, kt = (idx >> 9) & 7;
    int g = (idx >> 12) & 3, sl = idx >> 14;
    int n = g * 256 + sl * JS + (ln & 15);
    int k = kt * 32 + (ln >> 4) * 8 + e;
    dst[idx] = f2bf(src[n * 256 + k]);
}

__global__ void bias_sum(const float* a0, const float* b0, const float* a1, const float* b1,
                         const float* a2, const float* b2, const float* a3, const float* b3,
                         float* bias) {
    int idx = blockIdx.x * 256 + threadIdx.x;      // 0..4095
    int dl = idx >> 10, j = idx & 1023;
    const float* A = (dl == 0) ? a0 : (dl == 1) ? a1 : (dl == 2) ? a2 : a3;
    const float* B = (dl == 0) ? b0 : (dl == 1) ? b1 : (dl == 2) ? b2 : b3;
    bias[idx] = A[j] + B[j];
}

__global__ void calc_len(const int* x, int* lengths) {
    __shared__ int cnt;
    if (threadIdx.x == 0) cnt = 0;
    __syncthreads();
    if (x[blockIdx.x * Tv + threadIdx.x] > 0) atomicAdd(&cnt, 1);
    __syncthreads();
    if (threadIdx.x == 0) lengths[blockIdx.x] = cnt;
}

__global__ void zero_flags(int* flags) {
    flags[blockIdx.x * 256 + threadIdx.x] = 0;
}

// X0 row = [embed[tok](300) | f(1) | zeros(19)] as bf16
__global__ void embed_pack(const int* __restrict__ x, const float* __restrict__ f,
                           const float* __restrict__ embed, unsigned short* __restrict__ X0) {
    int row = blockIdx.x;
    int tok = x[row];
    float fv = f[row];
    const float* e = embed + (size_t)tok * Ev;
    for (int k = threadIdx.x; k < K0PAD; k += 64) {
        float v = (k < Ev) ? e[k] : ((k == Ev) ? fv : 0.f);
        X0[(size_t)row * K0PAD + k] = f2bf(v);
    }
}

// ---------------- MFMA GEMM: C[M,N] = X[M,K] @ W[N,K]^T + bias[N] ----------
__global__ __launch_bounds__(64) void mfma_gemm(
    const unsigned short* __restrict__ X, int ldx,
    const unsigned short* __restrict__ W, int ldw,
    const float* __restrict__ bias, float* __restrict__ C, int ldc, int K) {
    int lane = threadIdx.x;
    int m0 = blockIdx.x * 32, n0 = blockIdx.y * 32;
    int r = lane & 15, q = lane >> 4;
    const unsigned short* xa = X + (size_t)(m0 + r) * ldx + q * 8;
    const unsigned short* xb = xa + (size_t)16 * ldx;
    const unsigned short* wa = W + (size_t)(n0 + r) * ldw + q * 8;
    const unsigned short* wb = wa + (size_t)16 * ldw;
    v4f acc00 = {0.f, 0.f, 0.f, 0.f};
    v4f acc01 = acc00, acc10 = acc00, acc11 = acc00;
#pragma unroll 4
    for (int k = 0; k < K; k += 32) {
        v8bf a0 = *(const v8bf*)(xa + k);
        v8bf a1 = *(const v8bf*)(xb + k);
        v8bf b0 = *(const v8bf*)(wa + k);
        v8bf b1 = *(const v8bf*)(wb + k);
        acc00 = __builtin_amdgcn_mfma_f32_16x16x32_bf16(a0, b0, acc00, 0, 0, 0);
        acc01 = __builtin_amdgcn_mfma_f32_16x16x32_bf16(a0, b1, acc01, 0, 0, 0);
        acc10 = __builtin_amdgcn_mfma_f32_16x16x32_bf16(a1, b0, acc10, 0, 0, 0);
        acc11 = __builtin_amdgcn_mfma_f32_16x16x32_bf16(a1, b1, acc11, 0, 0, 0);
    }
    int col = n0 + r;
    float bv0 = bias[col], bv1 = bias[col + 16];
#pragma unroll
    for (int i = 0; i < 4; ++i) {
        int row = m0 + q * 4 + i;
        C[(size_t)row * ldc + col]             = acc00[i] + bv0;
        C[(size_t)row * ldc + col + 16]        = acc01[i] + bv1;
        C[(size_t)(row + 16) * ldc + col]      = acc10[i] + bv0;
        C[(size_t)(row + 16) * ldc + col + 16] = acc11[i] + bv1;
    }
}

// ---------------- slice-parallel LSTM (fence-free) ----------------
// grid (NSLICE, 2 dirs), block 256. Hstate [2][256][32][128] packed bf16-pair
// dwords, written/read ONLY with relaxed agent-scope atomics. flags
// [2][256][16], write-once per (step,slice).
__global__ __launch_bounds__(256) void lstm_slice(
    const float* __restrict__ Gin,
    const unsigned short* __restrict__ Wfrag,
    unsigned int* __restrict__ Hstate,
    unsigned int* __restrict__ Hout,
    int* __restrict__ flags,
    const int* __restrict__ lengths) {
    const int d = blockIdx.y, sl = blockIdx.x;
    const int tid = threadIdx.x;
    const int lane = tid & 63, g = tid >> 6;
    const int j0 = sl * JS;

    __shared__ __align__(16) unsigned short W[4][8][64][8];   // 32 KB B-fragments
    __shared__ float GT[4][32][17];                           // gate staging (+pad)

    // stage weights once: 32 KB contiguous
    {
        const uint4* src = (const uint4*)(Wfrag + (size_t)(d * NSLICE + sl) * WFRAG_PER_DS);
        uint4* dst = (uint4*)(&W[0][0][0][0]);
        for (int i = tid; i < 2048; i += 256) dst[i] = src[i];
    }
    // update-role mapping: one batch, two adjacent j
    const int ub = tid & 31, ujp = tid >> 5;                  // b, j-pair (0..7)
    const int ulen = lengths[ub];
    float cA = 0.f, hA = 0.f, cB = 0.f, hB = 0.f;
    int* myflags = flags + d * (256 * NSLICE);
    unsigned int* Hst = Hstate + (size_t)d * 256 * Bv * 128;
    const float* gin_d = Gin + (size_t)d * MROWS * GATES;
    const int ar = lane & 15, aq = lane >> 4;
    __syncthreads();

    for (int s = 0; s < 256; ++s) {
        const int t = d ? 255 - s : s;
        // Gin prefetch (independent of flags)
        float2 gv[4];
        const float2* gp = (const float2*)(gin_d + ((size_t)ub * Tv + t) * GATES + j0 + 2 * ujp);
#pragma unroll
        for (int q = 0; q < 4; ++q) gv[q] = gp[q * 128];

        if (s > 0) {
            // relaxed poll: lanes<16 of every wave watch the 16 slice flags
            if (lane < 16) {
                const int* fp = myflags + (s - 1) * NSLICE + lane;
                int spins = 0;
                while (__hip_atomic_load(fp, __ATOMIC_RELAXED, __HIP_MEMORY_SCOPE_AGENT) == 0) {
                    __builtin_amdgcn_s_sleep(2);
                    if (++spins > (1 << 22)) break;   // safety: terminate, don't hang
                }
            }
            // A fragments straight into registers (relaxed atomic dwords)
            const unsigned int* Hprev = Hst + (size_t)(s - 1) * Bv * 128;
            const unsigned int* Ar0 = Hprev + (size_t)ar * 128 + aq * 4;
            const unsigned int* Ar1 = Hprev + (size_t)(ar + 16) * 128 + aq * 4;
            unsigned int au0[8][4], au1[8][4];
#pragma unroll
            for (int kt = 0; kt < 8; ++kt) {
#pragma unroll
                for (int e = 0; e < 4; ++e) {
                    au0[kt][e] = __hip_atomic_load(Ar0 + kt * 16 + e,
                                                   __ATOMIC_RELAXED, __HIP_MEMORY_SCOPE_AGENT);
                    au1[kt][e] = __hip_atomic_load(Ar1 + kt * 16 + e,
                                                   __ATOMIC_RELAXED, __HIP_MEMORY_SCOPE_AGENT);
                }
            }
            v4f acc0 = {0.f, 0.f, 0.f, 0.f}, acc1 = acc0;
#pragma unroll
            for (int kt = 0; kt < 8; ++kt) {
                v8bf bfr = *(const v8bf*)(&W[g][kt][lane][0]);
                union { unsigned int u[4]; v8bf v; } c0, c1;
#pragma unroll
                for (int e = 0; e < 4; ++e) { c0.u[e] = au0[kt][e]; c1.u[e] = au1[kt][e]; }
                acc0 = __builtin_amdgcn_mfma_f32_16x16x32_bf16(c0.v, bfr, acc0, 0, 0, 0);
                acc1 = __builtin_amdgcn_mfma_f32_16x16x32_bf16(c1.v, bfr, acc1, 0, 0, 0);
            }
#pragma unroll
            for (int r = 0; r < 4; ++r) {          // C: col=lane&15 (j), row=quad*4+r (b)
                GT[g][aq * 4 + r][ar]      = acc0[r];
                GT[g][16 + aq * 4 + r][ar] = acc1[r];
            }
            __syncthreads();
        }
        // update (b=ub, j = j0+2*ujp and +1); state in registers
        {
            float pA[4], pB[4];
#pragma unroll
            for (int q = 0; q < 4; ++q) {
                float rA = (s > 0) ? GT[q][ub][2 * ujp]     : 0.f;
                float rB = (s > 0) ? GT[q][ub][2 * ujp + 1] : 0.f;
                pA[q] = gv[q].x + rA;
                pB[q] = gv[q].y + rB;
            }
            bool m = (t < ulen);
            {
                float ig = sigf(pA[0]), fg = sigf(pA[1]);
                float gg = tanhf2(pA[2]), og = sigf(pA[3]);
                float cn = fg * cA + ig * gg;
                float hn = og * tanhf2(cn);
                cA = m ? cn : cA; hA = m ? hn : hA;
            }
            {
                float ig = sigf(pB[0]), fg = sigf(pB[1]);
                float gg = tanhf2(pB[2]), og = sigf(pB[3]);
                float cn = fg * cB + ig * gg;
                float hn = og * tanhf2(cn);
                cB = m ? cn : cB; hB = m ? hn : hB;
            }
            unsigned int pk = (unsigned)f2bf(hA) | ((unsigned)f2bf(hB) << 16);
            __hip_atomic_store(Hst + (size_t)s * Bv * 128 + ub * 128 + sl * 8 + ujp, pk,
                               __ATOMIC_RELAXED, __HIP_MEMORY_SCOPE_AGENT);
            Hout[((size_t)ub * Tv + t) * 256 + d * 128 + sl * 8 + ujp] = m ? pk : 0u;
        }
        __syncthreads();   // all waves' stores drained (vmcnt(0) before s_barrier)
        if (tid == 0)
            __hip_atomic_store(myflags + s * NSLICE + sl, 1,
                               __ATOMIC_RELAXED, __HIP_MEMORY_SCOPE_AGENT);
    }
}

// ---------------- CRF ----------------
__global__ __launch_bounds__(64) void crf_kernel(
    const float* __restrict__ Y, const float* __restrict__ trans,
    const int* __restrict__ y0, const int* __restrict__ lengths,
    float* __restrict__ out) {
    int b = blockIdx.x, j = threadIdx.x;
    int len = lengths[b];
    float trj[64];
#pragma unroll
    for (int i = 0; i < 64; ++i) trj[i] = trans[j * 64 + i];
    __shared__ __align__(16) float s[64];
    s[j] = (j == 2) ? 0.f : -10000.f;
    __syncthreads();
    const float* yb = Y + (size_t)b * Tv * Kv;
    for (int t = 0; t < len; ++t) {
        float emit = yb[t * 64 + j];
        float m = -3.0e38f;
#pragma unroll
        for (int i = 0; i < 64; ++i) m = fmaxf(m, s[i] + trj[i]);
        float sum = 0.f;
#pragma unroll
        for (int i = 0; i < 64; ++i) sum += __expf(s[i] + trj[i] - m);
        float ns = m + __logf(sum) + emit;
        __syncthreads();
        s[j] = ns;
        __syncthreads();
    }
    float v = s[j];
    float M = v;
#pragma unroll
    for (int o = 32; o; o >>= 1) M = fmaxf(M, __shfl_xor(M, o));
    float e = __expf(v - M);
#pragma unroll
    for (int o = 32; o; o >>= 1) e += __shfl_xor(e, o);
    float Z = M + __logf(e);
    float gold = 0.f;
    for (int t = j; t < len; t += 64) {
        int yt = y0[b * Tv + t];
        int yp = (t == 0) ? 2 : y0[b * Tv + t - 1];
        gold += yb[t * 64 + yt] + trans[yt * 64 + yp];
    }
#pragma unroll
    for (int o = 32; o; o >>= 1) gold += __shfl_xor(gold, o);
    if (j == 0) out[b] = Z - gold;
}

// ---------------- host ----------------
extern "C" void kernel_launch(void* const* d_in, const int* in_sizes, int n_in,
                              void* d_out, int out_size, void* d_ws, size_t ws_size,
                              hipStream_t stream) {
    const int*   x     = (const int*)d_in[0];
    const float* f     = (const float*)d_in[1];
    const int*   y0    = (const int*)d_in[2];
    const float* embed = (const float*)d_in[3];
    const float* Wih0f = (const float*)d_in[4],  *Whh0f = (const float*)d_in[5];
    const float* bih0f = (const float*)d_in[6],  *bhh0f = (const float*)d_in[7];
    const float* Wih0b = (const float*)d_in[8],  *Whh0b = (const float*)d_in[9];
    const float* bih0b = (const float*)d_in[10], *bhh0b = (const float*)d_in[11];
    const float* Wih1f = (const float*)d_in[12], *Whh1f = (const float*)d_in[13];
    const float* bih1f = (const float*)d_in[14], *bhh1f = (const float*)d_in[15];
    const float* Wih1b = (const float*)d_in[16], *Whh1b = (const float*)d_in[17];
    const float* bih1b = (const float*)d_in[18], *bhh1b = (const float*)d_in[19];
    const float* out_w = (const float*)d_in[20];
    const float* out_b = (const float*)d_in[21];
    const float* trans = (const float*)d_in[22];

    char* ws = (char*)d_ws;
    size_t off = 0;
    auto alloc = [&](size_t bytes) -> void* {
        off = (off + 255) & ~(size_t)255;
        void* p = ws + off;
        off += bytes;
        return p;
    };
    unsigned short* X0   = (unsigned short*)alloc((size_t)MROWS * K0PAD * 2);
    unsigned short* dW0  = (unsigned short*)alloc((size_t)2 * 1024 * K0PAD * 2);
    unsigned short* dW1  = (unsigned short*)alloc((size_t)2 * 1024 * 512 * 2);
    unsigned short* dOW  = (unsigned short*)alloc((size_t)64 * 512 * 2);
    unsigned short* Wfrag= (unsigned short*)alloc((size_t)4 * NSLICE * WFRAG_PER_DS * 2);
    float*          bias = (float*)alloc((size_t)4096 * 4);
    int*            lens = (int*)alloc((size_t)32 * 4);
    int*            flags= (int*)alloc((size_t)2 * 2 * 256 * NSLICE * 4);
    unsigned int*   Hstate=(unsigned int*)alloc((size_t)2 * 256 * Bv * 128 * 4);
    float*          Gin  = (float*)alloc((size_t)2 * MROWS * GATES * 4);
    unsigned short* H0   = (unsigned short*)alloc((size_t)MROWS * 512 * 2);
    unsigned short* H1   = (unsigned short*)alloc((size_t)MROWS * 512 * 2);
    float*          Y    = (float*)alloc((size_t)MROWS * Kv * 4);
    (void)ws_size; (void)in_sizes; (void)n_in; (void)out_size;

    // prep
    conv_weights<<<dim3(2048, 1, 5), 256, 0, stream>>>(Wih0f, Wih0b, Wih1f, Wih1b, out_w,
                                                       dW0, dW1, dOW);
    whh_frag<<<dim3(1024, 1, 4), 256, 0, stream>>>(Whh0f, Whh0b, Whh1f, Whh1b, Wfrag);
    bias_sum<<<16, 256, 0, stream>>>(bih0f, bhh0f, bih0b, bhh0b,
                                     bih1f, bhh1f, bih1b, bhh1b, bias);
    calc_len<<<32, 256, 0, stream>>>(x, lens);
    zero_flags<<<64, 256, 0, stream>>>(flags);
    embed_pack<<<MROWS, 64, 0, stream>>>(x, f, embed, X0);

    // layer 0
    mfma_gemm<<<dim3(MROWS / 32, 32), 64, 0, stream>>>(X0, K0PAD, dW0, K0PAD,
                                                       bias, Gin, GATES, K0PAD);
    mfma_gemm<<<dim3(MROWS / 32, 32), 64, 0, stream>>>(X0, K0PAD, dW0 + 1024 * K0PAD, K0PAD,
                                                       bias + 1024, Gin + (size_t)MROWS * GATES,
                                                       GATES, K0PAD);
    lstm_slice<<<dim3(NSLICE, 2), 256, 0, stream>>>(Gin, Wfrag, Hstate,
                                                    (unsigned int*)H0, flags, lens);

    // layer 1
    mfma_gemm<<<dim3(MROWS / 32, 32), 64, 0, stream>>>(H0, 512, dW1, 512,
                                                       bias + 2048, Gin, GATES, 512);
    mfma_gemm<<<dim3(MROWS / 32, 32), 64, 0, stream>>>(H0, 512, dW1 + 1024 * 512, 512,
                                                       bias + 3072, Gin + (size_t)MROWS * GATES,
                                                       GATES, 512);
    lstm_slice<<<dim3(NSLICE, 2), 256, 0, stream>>>(Gin, Wfrag + (size_t)2 * NSLICE * WFRAG_PER_DS,
                                                    Hstate, (unsigned int*)H1,
                                                    flags + 2 * 256 * NSLICE, lens);

    // emissions + CRF
    mfma_gemm<<<dim3(MROWS / 32, 2), 64, 0, stream>>>(H1, 512, dOW, 512,
                                                      out_b, Y, Kv, 512);
    crf_kernel<<<32, 64, 0, stream>>>(Y, trans, y0, lens, (float*)d_out);
}

// Round 4
// 2482.734 us; speedup vs baseline: 2.1181x; 2.1181x over previous
//
#include <hip/hip_runtime.h>
#include <hip/hip_bf16.h>

// ---------------------------------------------------------------------------
// LSTM-CRF forward on MI355X.
// R4: fence-free slice-parallel LSTM, hybrid of R2/R3:
//   producer: packed bf16-pair h via relaxed agent-scope atomic store
//             (write-through to LLC), __syncthreads() vmcnt drain, then flag.
//   consumer: relaxed flag poll -> compiler barrier -> NORMAL coalesced
//             dwordx4 loads of A fragments straight into registers.
// No acquire/release fences (R2's 99MB refetch + stall), no atomic data
// loads (R3's 2.3x regression). Hstate step-slots shuffled (s*37 & 255)
// against stream prefetch; per-layer disjoint Hstate regions.
// ---------------------------------------------------------------------------

#define Bv 32
#define Tv 256
#define Ev 300
#define HDv 256
#define Kv 64
#define MROWS (Bv * Tv)          // 8192
#define K0PAD 320                // 301 padded to mult of 32
#define GATES 1024               // 4*HD
#define NSLICE 16                // j-slices per dir
#define JS 16                    // j per slice
#define WFRAG_PER_DS (4 * 8 * 64 * 8)   // shorts per (dir,slice) weight block

typedef __bf16 v8bf __attribute__((ext_vector_type(8)));
typedef float  v4f  __attribute__((ext_vector_type(4)));

__device__ __forceinline__ unsigned short f2bf(float f) {
    unsigned u = __float_as_uint(f);
    unsigned r = (u + 0x7fffu + ((u >> 16) & 1u)) >> 16;
    return (unsigned short)r;
}
__device__ __forceinline__ float sigf(float x) { return 1.0f / (1.0f + __expf(-x)); }
__device__ __forceinline__ float tanhf2(float x) {
    x = fminf(15.f, fmaxf(-15.f, x));
    float e = __expf(2.f * x);
    return (e - 1.f) / (e + 1.f);
}

// ---------------- prep kernels ----------------

__global__ void conv_weights(const float* w0f, const float* w0b,
                             const float* w1f, const float* w1b,
                             const float* outw,
                             unsigned short* dW0, unsigned short* dW1,
                             unsigned short* dOW) {
    int z = blockIdx.z;
    const float* src; unsigned short* dst; int rows, kin, kout;
    if (z == 0)      { src = w0f;  dst = dW0;                rows = 1024; kin = 301; kout = K0PAD; }
    else if (z == 1) { src = w0b;  dst = dW0 + 1024 * K0PAD; rows = 1024; kin = 301; kout = K0PAD; }
    else if (z == 2) { src = w1f;  dst = dW1;                rows = 1024; kin = 512; kout = 512; }
    else if (z == 3) { src = w1b;  dst = dW1 + 1024 * 512;   rows = 1024; kin = 512; kout = 512; }
    else             { src = outw; dst = dOW;                rows = 64;   kin = 512; kout = 512; }
    int idx = blockIdx.x * 256 + threadIdx.x;
    if (idx >= rows * kout) return;
    int j = idx / kout, k = idx - j * kout;
    dst[idx] = (k < kin) ? f2bf(src[j * kin + k]) : (unsigned short)0;
}

// Whh [1024,256] fp32 -> bf16 MFMA B-fragment order:
// per (layer*2+dir) z: [slice(16)][gate(4)][kt(8)][lane(64)][e(8)]
// value = Whh[gate*256 + slice*16 + (lane&15)][kt*32 + (lane>>4)*8 + e]
__global__ void whh_frag(const float* h0f, const float* h0b,
                         const float* h1f, const float* h1b, unsigned short* Wfrag) {
    int z = blockIdx.z;
    const float* src = (z == 0) ? h0f : (z == 1) ? h0b : (z == 2) ? h1f : h1b;
    unsigned short* dst = Wfrag + (size_t)z * (NSLICE * WFRAG_PER_DS);
    int idx = blockIdx.x * 256 + threadIdx.x;          // 0..262143
    int e = idx & 7, ln = (idx >> 3) & 63, kt = (idx >> 9) & 7;
    int g = (idx >> 12) & 3, sl = idx >> 14;
    int n = g * 256 + sl * JS + (ln & 15);
    int k = kt * 32 + (ln >> 4) * 8 + e;
    dst[idx] = f2bf(src[n * 256 + k]);
}

__global__ void bias_sum(const float* a0, const float* b0, const float* a1, const float* b1,
                         const float* a2, const float* b2, const float* a3, const float* b3,
                         float* bias) {
    int idx = blockIdx.x * 256 + threadIdx.x;      // 0..4095
    int dl = idx >> 10, j = idx & 1023;
    const float* A = (dl == 0) ? a0 : (dl == 1) ? a1 : (dl == 2) ? a2 : a3;
    const float* B = (dl == 0) ? b0 : (dl == 1) ? b1 : (dl == 2) ? b2 : b3;
    bias[idx] = A[j] + B[j];
}

__global__ void calc_len(const int* x, int* lengths) {
    __shared__ int cnt;
    if (threadIdx.x == 0) cnt = 0;
    __syncthreads();
    if (x[blockIdx.x * Tv + threadIdx.x] > 0) atomicAdd(&cnt, 1);
    __syncthreads();
    if (threadIdx.x == 0) lengths[blockIdx.x] = cnt;
}

__global__ void zero_flags(int* flags) {
    flags[blockIdx.x * 256 + threadIdx.x] = 0;
}

// X0 row = [embed[tok](300) | f(1) | zeros(19)] as bf16
__global__ void embed_pack(const int* __restrict__ x, const float* __restrict__ f,
                           const float* __restrict__ embed, unsigned short* __restrict__ X0) {
    int row = blockIdx.x;
    int tok = x[row];
    float fv = f[row];
    const float* e = embed + (size_t)tok * Ev;
    for (int k = threadIdx.x; k < K0PAD; k += 64) {
        float v = (k < Ev) ? e[k] : ((k == Ev) ? fv : 0.f);
        X0[(size_t)row * K0PAD + k] = f2bf(v);
    }
}

// ---------------- MFMA GEMM: C[M,N] = X[M,K] @ W[N,K]^T + bias[N] ----------
__global__ __launch_bounds__(64) void mfma_gemm(
    const unsigned short* __restrict__ X, int ldx,
    const unsigned short* __restrict__ W, int ldw,
    const float* __restrict__ bias, float* __restrict__ C, int ldc, int K) {
    int lane = threadIdx.x;
    int m0 = blockIdx.x * 32, n0 = blockIdx.y * 32;
    int r = lane & 15, q = lane >> 4;
    const unsigned short* xa = X + (size_t)(m0 + r) * ldx + q * 8;
    const unsigned short* xb = xa + (size_t)16 * ldx;
    const unsigned short* wa = W + (size_t)(n0 + r) * ldw + q * 8;
    const unsigned short* wb = wa + (size_t)16 * ldw;
    v4f acc00 = {0.f, 0.f, 0.f, 0.f};
    v4f acc01 = acc00, acc10 = acc00, acc11 = acc00;
#pragma unroll 4
    for (int k = 0; k < K; k += 32) {
        v8bf a0 = *(const v8bf*)(xa + k);
        v8bf a1 = *(const v8bf*)(xb + k);
        v8bf b0 = *(const v8bf*)(wa + k);
        v8bf b1 = *(const v8bf*)(wb + k);
        acc00 = __builtin_amdgcn_mfma_f32_16x16x32_bf16(a0, b0, acc00, 0, 0, 0);
        acc01 = __builtin_amdgcn_mfma_f32_16x16x32_bf16(a0, b1, acc01, 0, 0, 0);
        acc10 = __builtin_amdgcn_mfma_f32_16x16x32_bf16(a1, b0, acc10, 0, 0, 0);
        acc11 = __builtin_amdgcn_mfma_f32_16x16x32_bf16(a1, b1, acc11, 0, 0, 0);
    }
    int col = n0 + r;
    float bv0 = bias[col], bv1 = bias[col + 16];
#pragma unroll
    for (int i = 0; i < 4; ++i) {
        int row = m0 + q * 4 + i;
        C[(size_t)row * ldc + col]             = acc00[i] + bv0;
        C[(size_t)row * ldc + col + 16]        = acc01[i] + bv1;
        C[(size_t)(row + 16) * ldc + col]      = acc10[i] + bv0;
        C[(size_t)(row + 16) * ldc + col + 16] = acc11[i] + bv1;
    }
}

// ---------------- slice-parallel LSTM (R4) ----------------
// grid (NSLICE, 2 dirs), block 256. Hstate [256 slots][32][128] packed
// bf16-pair dwords per dir; slot = (s*37)&255. Producer: atomic relaxed
// store. Consumer: relaxed flag poll + normal dwordx4 fragment loads.
__global__ __launch_bounds__(256) void lstm_slice(
    const float* __restrict__ Gin,
    const unsigned short* __restrict__ Wfrag,
    unsigned int* __restrict__ Hstate,
    unsigned int* __restrict__ Hout,
    int* __restrict__ flags,
    const int* __restrict__ lengths) {
    const int d = blockIdx.y, sl = blockIdx.x;
    const int tid = threadIdx.x;
    const int lane = tid & 63, g = tid >> 6;
    const int j0 = sl * JS;

    __shared__ __align__(16) unsigned short W[4][8][64][8];   // 32 KB B-fragments
    __shared__ float GT[4][32][17];                           // gate staging (+pad)

    // stage weights once: 32 KB contiguous
    {
        const uint4* src = (const uint4*)(Wfrag + (size_t)(d * NSLICE + sl) * WFRAG_PER_DS);
        uint4* dst = (uint4*)(&W[0][0][0][0]);
        for (int i = tid; i < 2048; i += 256) dst[i] = src[i];
    }
    // update-role mapping: one batch, two adjacent j
    const int ub = tid & 31, ujp = tid >> 5;                  // b, j-pair (0..7)
    const int ulen = lengths[ub];
    float cA = 0.f, hA = 0.f, cB = 0.f, hB = 0.f;
    int* myflags = flags + d * (256 * NSLICE);
    unsigned int* Hst = Hstate + (size_t)d * 256 * Bv * 128;
    const float* gin_d = Gin + (size_t)d * MROWS * GATES;
    const int ar = lane & 15, aq = lane >> 4;
    __syncthreads();

    for (int s = 0; s < 256; ++s) {
        const int t = d ? 255 - s : s;
        const int slot  = (s * 37) & 255;
        // Gin prefetch (independent of flags; issues before polling)
        float2 gv[4];
        const float2* gp = (const float2*)(gin_d + ((size_t)ub * Tv + t) * GATES + j0 + 2 * ujp);
#pragma unroll
        for (int q = 0; q < 4; ++q) gv[q] = gp[q * 128];

        if (s > 0) {
            const int pslot = ((s - 1) * 37) & 255;
            // relaxed poll: lanes<16 of every wave watch the 16 slice flags.
            // wave lockstep: no lane proceeds until all 16 flags observed.
            if (lane < 16) {
                const int* fp = myflags + (s - 1) * NSLICE + lane;
                int spins = 0;
                while (__hip_atomic_load(fp, __ATOMIC_RELAXED, __HIP_MEMORY_SCOPE_AGENT) == 0) {
                    __builtin_amdgcn_s_sleep(1);
                    if (++spins > (1 << 24)) break;   // safety valve
                }
            }
            __asm__ __volatile__("" ::: "memory");    // no load hoisting above poll
            // A fragments straight into registers, normal coalesced loads
            const uint4* Hp = (const uint4*)(Hst + (size_t)pslot * Bv * 128);
            const uint4* r0 = Hp + ar * 32 + aq;
            const uint4* r1 = Hp + (ar + 16) * 32 + aq;
            uint4 au0[8], au1[8];
#pragma unroll
            for (int kt = 0; kt < 8; ++kt) { au0[kt] = r0[kt * 4]; au1[kt] = r1[kt * 4]; }
            v4f acc0 = {0.f, 0.f, 0.f, 0.f}, acc1 = acc0;
#pragma unroll
            for (int kt = 0; kt < 8; ++kt) {
                v8bf bfr = *(const v8bf*)(&W[g][kt][lane][0]);
                union { uint4 u; v8bf v; } c0, c1;
                c0.u = au0[kt]; c1.u = au1[kt];
                acc0 = __builtin_amdgcn_mfma_f32_16x16x32_bf16(c0.v, bfr, acc0, 0, 0, 0);
                acc1 = __builtin_amdgcn_mfma_f32_16x16x32_bf16(c1.v, bfr, acc1, 0, 0, 0);
            }
#pragma unroll
            for (int r = 0; r < 4; ++r) {          // C: col=lane&15 (j), row=quad*4+r (b)
                GT[g][aq * 4 + r][ar]      = acc0[r];
                GT[g][16 + aq * 4 + r][ar] = acc1[r];
            }
            __syncthreads();
        }
        // update (b=ub, j = j0+2*ujp and +1); state in registers
        unsigned int pk;
        {
            float pA[4], pB[4];
#pragma unroll
            for (int q = 0; q < 4; ++q) {
                float rA = (s > 0) ? GT[q][ub][2 * ujp]     : 0.f;
                float rB = (s > 0) ? GT[q][ub][2 * ujp + 1] : 0.f;
                pA[q] = gv[q].x + rA;
                pB[q] = gv[q].y + rB;
            }
            bool m = (t < ulen);
            {
                float ig = sigf(pA[0]), fg = sigf(pA[1]);
                float gg = tanhf2(pA[2]), og = sigf(pA[3]);
                float cn = fg * cA + ig * gg;
                float hn = og * tanhf2(cn);
                cA = m ? cn : cA; hA = m ? hn : hA;
            }
            {
                float ig = sigf(pB[0]), fg = sigf(pB[1]);
                float gg = tanhf2(pB[2]), og = sigf(pB[3]);
                float cn = fg * cB + ig * gg;
                float hn = og * tanhf2(cn);
                cB = m ? cn : cB; hB = m ? hn : hB;
            }
            pk = (unsigned)f2bf(hA) | ((unsigned)f2bf(hB) << 16);
            __hip_atomic_store(Hst + (size_t)slot * Bv * 128 + ub * 128 + sl * 8 + ujp, pk,
                               __ATOMIC_RELAXED, __HIP_MEMORY_SCOPE_AGENT);
        }
        __syncthreads();   // vmcnt(0) drain: all waves' h stores at LLC
        if (tid == 0)
            __hip_atomic_store(myflags + s * NSLICE + sl, 1,
                               __ATOMIC_RELAXED, __HIP_MEMORY_SCOPE_AGENT);
        // Hout off the critical path (consumed by next dispatch only)
        {
            bool m = (t < ulen);
            Hout[((size_t)ub * Tv + t) * 256 + d * 128 + sl * 8 + ujp] = m ? pk : 0u;
        }
    }
}

// ---------------- CRF ----------------
__global__ __launch_bounds__(64) void crf_kernel(
    const float* __restrict__ Y, const float* __restrict__ trans,
    const int* __restrict__ y0, const int* __restrict__ lengths,
    float* __restrict__ out) {
    int b = blockIdx.x, j = threadIdx.x;
    int len = lengths[b];
    float trj[64];
#pragma unroll
    for (int i = 0; i < 64; ++i) trj[i] = trans[j * 64 + i];
    __shared__ __align__(16) float s[64];
    s[j] = (j == 2) ? 0.f : -10000.f;
    __syncthreads();
    const float* yb = Y + (size_t)b * Tv * Kv;
    for (int t = 0; t < len; ++t) {
        float emit = yb[t * 64 + j];
        float m = -3.0e38f;
#pragma unroll
        for (int i = 0; i < 64; ++i) m = fmaxf(m, s[i] + trj[i]);
        float sum = 0.f;
#pragma unroll
        for (int i = 0; i < 64; ++i) sum += __expf(s[i] + trj[i] - m);
        float ns = m + __logf(sum) + emit;
        __syncthreads();
        s[j] = ns;
        __syncthreads();
    }
    float v = s[j];
    float M = v;
#pragma unroll
    for (int o = 32; o; o >>= 1) M = fmaxf(M, __shfl_xor(M, o));
    float e = __expf(v - M);
#pragma unroll
    for (int o = 32; o; o >>= 1) e += __shfl_xor(e, o);
    float Z = M + __logf(e);
    float gold = 0.f;
    for (int t = j; t < len; t += 64) {
        int yt = y0[b * Tv + t];
        int yp = (t == 0) ? 2 : y0[b * Tv + t - 1];
        gold += yb[t * 64 + yt] + trans[yt * 64 + yp];
    }
#pragma unroll
    for (int o = 32; o; o >>= 1) gold += __shfl_xor(gold, o);
    if (j == 0) out[b] = Z - gold;
}

// ---------------- host ----------------
extern "C" void kernel_launch(void* const* d_in, const int* in_sizes, int n_in,
                              void* d_out, int out_size, void* d_ws, size_t ws_size,
                              hipStream_t stream) {
    const int*   x     = (const int*)d_in[0];
    const float* f     = (const float*)d_in[1];
    const int*   y0    = (const int*)d_in[2];
    const float* embed = (const float*)d_in[3];
    const float* Wih0f = (const float*)d_in[4],  *Whh0f = (const float*)d_in[5];
    const float* bih0f = (const float*)d_in[6],  *bhh0f = (const float*)d_in[7];
    const float* Wih0b = (const float*)d_in[8],  *Whh0b = (const float*)d_in[9];
    const float* bih0b = (const float*)d_in[10], *bhh0b = (const float*)d_in[11];
    const float* Wih1f = (const float*)d_in[12], *Whh1f = (const float*)d_in[13];
    const float* bih1f = (const float*)d_in[14], *bhh1f = (const float*)d_in[15];
    const float* Wih1b = (const float*)d_in[16], *Whh1b = (const float*)d_in[17];
    const float* bih1b = (const float*)d_in[18], *bhh1b = (const float*)d_in[19];
    const float* out_w = (const float*)d_in[20];
    const float* out_b = (const float*)d_in[21];
    const float* trans = (const float*)d_in[22];

    char* ws = (char*)d_ws;
    size_t off = 0;
    auto alloc = [&](size_t bytes) -> void* {
        off = (off + 255) & ~(size_t)255;
        void* p = ws + off;
        off += bytes;
        return p;
    };
    unsigned short* X0   = (unsigned short*)alloc((size_t)MROWS * K0PAD * 2);
    unsigned short* dW0  = (unsigned short*)alloc((size_t)2 * 1024 * K0PAD * 2);
    unsigned short* dW1  = (unsigned short*)alloc((size_t)2 * 1024 * 512 * 2);
    unsigned short* dOW  = (unsigned short*)alloc((size_t)64 * 512 * 2);
    unsigned short* Wfrag= (unsigned short*)alloc((size_t)4 * NSLICE * WFRAG_PER_DS * 2);
    float*          bias = (float*)alloc((size_t)4096 * 4);
    int*            lens = (int*)alloc((size_t)32 * 4);
    int*            flags= (int*)alloc((size_t)2 * 2 * 256 * NSLICE * 4);
    unsigned int*   Hst0 = (unsigned int*)alloc((size_t)2 * 256 * Bv * 128 * 4);
    unsigned int*   Hst1 = (unsigned int*)alloc((size_t)2 * 256 * Bv * 128 * 4);
    float*          Gin  = (float*)alloc((size_t)2 * MROWS * GATES * 4);
    unsigned short* H0   = (unsigned short*)alloc((size_t)MROWS * 512 * 2);
    unsigned short* H1   = (unsigned short*)alloc((size_t)MROWS * 512 * 2);
    float*          Y    = (float*)alloc((size_t)MROWS * Kv * 4);
    (void)ws_size; (void)in_sizes; (void)n_in; (void)out_size;

    // prep
    conv_weights<<<dim3(2048, 1, 5), 256, 0, stream>>>(Wih0f, Wih0b, Wih1f, Wih1b, out_w,
                                                       dW0, dW1, dOW);
    whh_frag<<<dim3(1024, 1, 4), 256, 0, stream>>>(Whh0f, Whh0b, Whh1f, Whh1b, Wfrag);
    bias_sum<<<16, 256, 0, stream>>>(bih0f, bhh0f, bih0b, bhh0b,
                                     bih1f, bhh1f, bih1b, bhh1b, bias);
    calc_len<<<32, 256, 0, stream>>>(x, lens);
    zero_flags<<<64, 256, 0, stream>>>(flags);
    embed_pack<<<MROWS, 64, 0, stream>>>(x, f, embed, X0);

    // layer 0
    mfma_gemm<<<dim3(MROWS / 32, 32), 64, 0, stream>>>(X0, K0PAD, dW0, K0PAD,
                                                       bias, Gin, GATES, K0PAD);
    mfma_gemm<<<dim3(MROWS / 32, 32), 64, 0, stream>>>(X0, K0PAD, dW0 + 1024 * K0PAD, K0PAD,
                                                       bias + 1024, Gin + (size_t)MROWS * GATES,
                                                       GATES, K0PAD);
    lstm_slice<<<dim3(NSLICE, 2), 256, 0, stream>>>(Gin, Wfrag, Hst0,
                                                    (unsigned int*)H0, flags, lens);

    // layer 1
    mfma_gemm<<<dim3(MROWS / 32, 32), 64, 0, stream>>>(H0, 512, dW1, 512,
                                                       bias + 2048, Gin, GATES, 512);
    mfma_gemm<<<dim3(MROWS / 32, 32), 64, 0, stream>>>(H0, 512, dW1 + 1024 * 512, 512,
                                                       bias + 3072, Gin + (size_t)MROWS * GATES,
                                                       GATES, 512);
    lstm_slice<<<dim3(NSLICE, 2), 256, 0, stream>>>(Gin, Wfrag + (size_t)2 * NSLICE * WFRAG_PER_DS,
                                                    Hst1, (unsigned int*)H1,
                                                    flags + 2 * 256 * NSLICE, lens);

    // emissions + CRF
    mfma_gemm<<<dim3(MROWS / 32, 2), 64, 0, stream>>>(H1, 512, dOW, 512,
                                                      out_b, Y, Kv, 512);
    crf_kernel<<<32, 64, 0, stream>>>(Y, trans, y0, lens, (float*)d_out);
}

// Round 5
// 1770.688 us; speedup vs baseline: 2.9698x; 1.4021x over previous
//
#include <hip/hip_runtime.h>
#include <hip/hip_bf16.h>

// ---------------------------------------------------------------------------
// LSTM-CRF forward on MI355X.
// R5: slice-parallel LSTM, latency-trimmed:
//  - h stored in MFMA A-fragment order; consumer stages ONE 16 KB copy via
//    global_load_lds (was 64 KB/step redundant register loads in R4).
//  - Whh fragments in registers (loaded once per wave).
//  - hard-spin flag poll (no s_sleep), flags padded to a line per step.
//  - sync protocol unchanged from R4 (proven): relaxed atomic write-through
//    h stores -> __syncthreads vmcnt drain -> relaxed flag; consumer relaxed
//    poll -> compiler barrier -> first-touch loads of shuffled step slots.
// ---------------------------------------------------------------------------

#define Bv 32
#define Tv 256
#define Ev 300
#define HDv 256
#define Kv 64
#define MROWS (Bv * Tv)          // 8192
#define K0PAD 320                // 301 padded to mult of 32
#define GATES 1024               // 4*HD
#define NSLICE 16                // j-slices per dir
#define JS 16                    // j per slice
#define FLAGSTRIDE 32            // dwords per step (128B line)
#define WFRAG_PER_DS (4 * 8 * 64 * 8)   // shorts per (dir,slice) weight block

typedef __bf16 v8bf __attribute__((ext_vector_type(8)));
typedef float  v4f  __attribute__((ext_vector_type(4)));

__device__ __forceinline__ unsigned short f2bf(float f) {
    unsigned u = __float_as_uint(f);
    unsigned r = (u + 0x7fffu + ((u >> 16) & 1u)) >> 16;
    return (unsigned short)r;
}
__device__ __forceinline__ float sigf(float x) { return 1.0f / (1.0f + __expf(-x)); }
__device__ __forceinline__ float tanhf2(float x) {
    x = fminf(15.f, fmaxf(-15.f, x));
    float e = __expf(2.f * x);
    return (e - 1.f) / (e + 1.f);
}
__device__ __forceinline__ void gl_lds16(const unsigned int* g, unsigned int* l) {
    __builtin_amdgcn_global_load_lds(
        (const __attribute__((address_space(1))) unsigned int*)g,
        (__attribute__((address_space(3))) unsigned int*)l, 16, 0, 0);
}

// ---------------- prep kernels ----------------

__global__ void conv_weights(const float* w0f, const float* w0b,
                             const float* w1f, const float* w1b,
                             const float* outw,
                             unsigned short* dW0, unsigned short* dW1,
                             unsigned short* dOW) {
    int z = blockIdx.z;
    const float* src; unsigned short* dst; int rows, kin, kout;
    if (z == 0)      { src = w0f;  dst = dW0;                rows = 1024; kin = 301; kout = K0PAD; }
    else if (z == 1) { src = w0b;  dst = dW0 + 1024 * K0PAD; rows = 1024; kin = 301; kout = K0PAD; }
    else if (z == 2) { src = w1f;  dst = dW1;                rows = 1024; kin = 512; kout = 512; }
    else if (z == 3) { src = w1b;  dst = dW1 + 1024 * 512;   rows = 1024; kin = 512; kout = 512; }
    else             { src = outw; dst = dOW;                rows = 64;   kin = 512; kout = 512; }
    int idx = blockIdx.x * 256 + threadIdx.x;
    if (idx >= rows * kout) return;
    int j = idx / kout, k = idx - j * kout;
    dst[idx] = (k < kin) ? f2bf(src[j * kin + k]) : (unsigned short)0;
}

// Whh [1024,256] fp32 -> bf16 MFMA B-fragment order:
// per (layer*2+dir) z: [slice(16)][gate(4)][kt(8)][lane(64)][e(8)]
// value = Whh[gate*256 + slice*16 + (lane&15)][kt*32 + (lane>>4)*8 + e]
__global__ void whh_frag(const float* h0f, const float* h0b,
                         const float* h1f, const float* h1b, unsigned short* Wfrag) {
    int z = blockIdx.z;
    const float* src = (z == 0) ? h0f : (z == 1) ? h0b : (z == 2) ? h1f : h1b;
    unsigned short* dst = Wfrag + (size_t)z * (NSLICE * WFRAG_PER_DS);
    int idx = blockIdx.x * 256 + threadIdx.x;          // 0..262143
    int e = idx & 7, ln = (idx >> 3) & 63, kt = (idx >> 9) & 7;
    int g = (idx >> 12) & 3, sl = idx >> 14;
    int n = g * 256 + sl * JS + (ln & 15);
    int k = kt * 32 + (ln >> 4) * 8 + e;
    dst[idx] = f2bf(src[n * 256 + k]);
}

__global__ void bias_sum(const float* a0, const float* b0, const float* a1, const float* b1,
                         const float* a2, const float* b2, const float* a3, const float* b3,
                         float* bias) {
    int idx = blockIdx.x * 256 + threadIdx.x;      // 0..4095
    int dl = idx >> 10, j = idx & 1023;
    const float* A = (dl == 0) ? a0 : (dl == 1) ? a1 : (dl == 2) ? a2 : a3;
    const float* B = (dl == 0) ? b0 : (dl == 1) ? b1 : (dl == 2) ? b2 : b3;
    bias[idx] = A[j] + B[j];
}

__global__ void calc_len(const int* x, int* lengths) {
    __shared__ int cnt;
    if (threadIdx.x == 0) cnt = 0;
    __syncthreads();
    if (x[blockIdx.x * Tv + threadIdx.x] > 0) atomicAdd(&cnt, 1);
    __syncthreads();
    if (threadIdx.x == 0) lengths[blockIdx.x] = cnt;
}

__global__ void zero_flags(int* flags) {
    flags[blockIdx.x * 256 + threadIdx.x] = 0;
}

// X0 row = [embed[tok](300) | f(1) | zeros(19)] as bf16
__global__ void embed_pack(const int* __restrict__ x, const float* __restrict__ f,
                           const float* __restrict__ embed, unsigned short* __restrict__ X0) {
    int row = blockIdx.x;
    int tok = x[row];
    float fv = f[row];
    const float* e = embed + (size_t)tok * Ev;
    for (int k = threadIdx.x; k < K0PAD; k += 64) {
        float v = (k < Ev) ? e[k] : ((k == Ev) ? fv : 0.f);
        X0[(size_t)row * K0PAD + k] = f2bf(v);
    }
}

// ---------------- MFMA GEMM: C[M,N] = X[M,K] @ W[N,K]^T + bias[N] ----------
__global__ __launch_bounds__(64) void mfma_gemm(
    const unsigned short* __restrict__ X, int ldx,
    const unsigned short* __restrict__ W, int ldw,
    const float* __restrict__ bias, float* __restrict__ C, int ldc, int K) {
    int lane = threadIdx.x;
    int m0 = blockIdx.x * 32, n0 = blockIdx.y * 32;
    int r = lane & 15, q = lane >> 4;
    const unsigned short* xa = X + (size_t)(m0 + r) * ldx + q * 8;
    const unsigned short* xb = xa + (size_t)16 * ldx;
    const unsigned short* wa = W + (size_t)(n0 + r) * ldw + q * 8;
    const unsigned short* wb = wa + (size_t)16 * ldw;
    v4f acc00 = {0.f, 0.f, 0.f, 0.f};
    v4f acc01 = acc00, acc10 = acc00, acc11 = acc00;
#pragma unroll 4
    for (int k = 0; k < K; k += 32) {
        v8bf a0 = *(const v8bf*)(xa + k);
        v8bf a1 = *(const v8bf*)(xb + k);
        v8bf b0 = *(const v8bf*)(wa + k);
        v8bf b1 = *(const v8bf*)(wb + k);
        acc00 = __builtin_amdgcn_mfma_f32_16x16x32_bf16(a0, b0, acc00, 0, 0, 0);
        acc01 = __builtin_amdgcn_mfma_f32_16x16x32_bf16(a0, b1, acc01, 0, 0, 0);
        acc10 = __builtin_amdgcn_mfma_f32_16x16x32_bf16(a1, b0, acc10, 0, 0, 0);
        acc11 = __builtin_amdgcn_mfma_f32_16x16x32_bf16(a1, b1, acc11, 0, 0, 0);
    }
    int col = n0 + r;
    float bv0 = bias[col], bv1 = bias[col + 16];
#pragma unroll
    for (int i = 0; i < 4; ++i) {
        int row = m0 + q * 4 + i;
        C[(size_t)row * ldc + col]             = acc00[i] + bv0;
        C[(size_t)row * ldc + col + 16]        = acc01[i] + bv1;
        C[(size_t)(row + 16) * ldc + col]      = acc10[i] + bv0;
        C[(size_t)(row + 16) * ldc + col + 16] = acc11[i] + bv1;
    }
}

// ---------------- slice-parallel LSTM (R5) ----------------
// Hstate slot layout = MFMA A-fragment order (4096 dwords):
//   dword(r,c) = (r>=16 ? 2048 : 0) + ((c>>4)*64 + ((c>>2)&3)*16 + (r&15))*4 + (c&3)
// where r=batch, c=packed j-pair column (j = 2c, 2c+1).
__global__ __launch_bounds__(256) void lstm_slice(
    const float* __restrict__ Gin,
    const unsigned short* __restrict__ Wfrag,
    unsigned int* __restrict__ Hstate,
    unsigned int* __restrict__ Hout,
    int* __restrict__ flags,
    const int* __restrict__ lengths) {
    const int d = blockIdx.y, sl = blockIdx.x;
    const int tid = threadIdx.x;
    const int lane = tid & 63, g = tid >> 6;
    const int j0 = sl * JS;

    __shared__ __align__(16) unsigned int Afrag[4096];   // 16 KB, fragment order
    __shared__ float GT[4][32][17];                      // gate staging (+pad)

    // Whh B-fragments -> registers (8 kt x 16B per lane)
    v8bf wreg[8];
    {
        const unsigned short* wb = Wfrag + (size_t)(d * NSLICE + sl) * WFRAG_PER_DS
                                 + ((size_t)g * 8 * 64 + lane) * 8;
#pragma unroll
        for (int kt = 0; kt < 8; ++kt)
            wreg[kt] = *(const v8bf*)(wb + (size_t)kt * 64 * 8);
    }
    // update-role mapping: one batch, two adjacent j
    const int ub = tid & 31, ujp = tid >> 5;                  // b, j-pair (0..7)
    const int ulen = lengths[ub];
    float cA = 0.f, hA = 0.f, cB = 0.f, hB = 0.f;
    int* myflags = flags + d * (256 * FLAGSTRIDE);
    unsigned int* Hst = Hstate + (size_t)d * 256 * 4096;
    const float* gin_d = Gin + (size_t)d * MROWS * GATES;
    // producer fragment-index for (ub, c=sl*8+ujp)
    const int pc = sl * 8 + ujp;
    const int pidx = ((ub & 16) ? 2048 : 0)
                   + (((pc >> 4) * 64 + ((pc >> 2) & 3) * 16 + (ub & 15)) << 2) + (pc & 3);

    for (int s = 0; s < 256; ++s) {
        const int t = d ? 255 - s : s;
        const int slot = (s * 37) & 255;
        // Gin prefetch (independent of flags; issues before polling)
        float2 gv[4];
        const float2* gp = (const float2*)(gin_d + ((size_t)ub * Tv + t) * GATES + j0 + 2 * ujp);
#pragma unroll
        for (int q = 0; q < 4; ++q) gv[q] = gp[q * 128];

        if (s > 0) {
            const int pslot = ((s - 1) * 37) & 255;
            // hard-spin relaxed poll: lanes<16 of every wave watch 16 slice flags
            if (lane < 16) {
                const int* fp = myflags + (s - 1) * FLAGSTRIDE + lane;
                int spins = 0;
                while (__hip_atomic_load(fp, __ATOMIC_RELAXED, __HIP_MEMORY_SCOPE_AGENT) == 0) {
                    if (++spins > (1 << 22)) break;   // safety valve
                }
            }
            __asm__ __volatile__("" ::: "memory");    // no hoisting above poll
            // stage h(t-1): 16 KB contiguous via global_load_lds, 4 segs/wave
            const unsigned int* Hp = Hst + (size_t)pslot * 4096;
#pragma unroll
            for (int i = 0; i < 4; ++i) {
                int seg = g * 4 + i;
                gl_lds16(Hp + (seg * 64 + lane) * 4, &Afrag[seg * 256]);
            }
            __syncthreads();                          // drains vmcnt: Afrag ready
            // fragments + MFMA (A shared by all 4 waves; B in registers)
            v4f acc0 = {0.f, 0.f, 0.f, 0.f}, acc1 = acc0;
            const uint4* Af = (const uint4*)Afrag;
#pragma unroll
            for (int kt = 0; kt < 8; ++kt) {
                union { uint4 u; v8bf v; } c0, c1;
                c0.u = Af[kt * 64 + lane];
                c1.u = Af[512 + kt * 64 + lane];
                acc0 = __builtin_amdgcn_mfma_f32_16x16x32_bf16(c0.v, wreg[kt], acc0, 0, 0, 0);
                acc1 = __builtin_amdgcn_mfma_f32_16x16x32_bf16(c1.v, wreg[kt], acc1, 0, 0, 0);
            }
            const int ar = lane & 15, aq = lane >> 4;
#pragma unroll
            for (int r = 0; r < 4; ++r) {          // C: col=lane&15 (j), row=quad*4+r (b)
                GT[g][aq * 4 + r][ar]      = acc0[r];
                GT[g][16 + aq * 4 + r][ar] = acc1[r];
            }
            __syncthreads();
        }
        // update (b=ub, j = j0+2*ujp and +1); state in registers
        unsigned int pk;
        {
            float pA[4], pB[4];
#pragma unroll
            for (int q = 0; q < 4; ++q) {
                float rA = (s > 0) ? GT[q][ub][2 * ujp]     : 0.f;
                float rB = (s > 0) ? GT[q][ub][2 * ujp + 1] : 0.f;
                pA[q] = gv[q].x + rA;
                pB[q] = gv[q].y + rB;
            }
            bool m = (t < ulen);
            {
                float ig = sigf(pA[0]), fg = sigf(pA[1]);
                float gg = tanhf2(pA[2]), og = sigf(pA[3]);
                float cn = fg * cA + ig * gg;
                float hn = og * tanhf2(cn);
                cA = m ? cn : cA; hA = m ? hn : hA;
            }
            {
                float ig = sigf(pB[0]), fg = sigf(pB[1]);
                float gg = tanhf2(pB[2]), og = sigf(pB[3]);
                float cn = fg * cB + ig * gg;
                float hn = og * tanhf2(cn);
                cB = m ? cn : cB; hB = m ? hn : hB;
            }
            pk = (unsigned)f2bf(hA) | ((unsigned)f2bf(hB) << 16);
            __hip_atomic_store(Hst + (size_t)slot * 4096 + pidx, pk,
                               __ATOMIC_RELAXED, __HIP_MEMORY_SCOPE_AGENT);
        }
        __syncthreads();   // vmcnt(0) drain: all waves' h stores at coherence point
        if (tid == 0)
            __hip_atomic_store(myflags + s * FLAGSTRIDE + sl, 1,
                               __ATOMIC_RELAXED, __HIP_MEMORY_SCOPE_AGENT);
        // Hout off the critical path (consumed by next dispatch only)
        {
            bool m = (t < ulen);
            Hout[((size_t)ub * Tv + t) * 256 + d * 128 + sl * 8 + ujp] = m ? pk : 0u;
        }
    }
}

// ---------------- CRF ----------------
__global__ __launch_bounds__(64) void crf_kernel(
    const float* __restrict__ Y, const float* __restrict__ trans,
    const int* __restrict__ y0, const int* __restrict__ lengths,
    float* __restrict__ out) {
    int b = blockIdx.x, j = threadIdx.x;
    int len = lengths[b];
    float trj[64];
#pragma unroll
    for (int i = 0; i < 64; ++i) trj[i] = trans[j * 64 + i];
    __shared__ __align__(16) float s[64];
    s[j] = (j == 2) ? 0.f : -10000.f;
    __syncthreads();
    const float* yb = Y + (size_t)b * Tv * Kv;
    for (int t = 0; t < len; ++t) {
        float emit = yb[t * 64 + j];
        float m = -3.0e38f;
#pragma unroll
        for (int i = 0; i < 64; ++i) m = fmaxf(m, s[i] + trj[i]);
        float sum = 0.f;
#pragma unroll
        for (int i = 0; i < 64; ++i) sum += __expf(s[i] + trj[i] - m);
        float ns = m + __logf(sum) + emit;
        __syncthreads();
        s[j] = ns;
        __syncthreads();
    }
    float v = s[j];
    float M = v;
#pragma unroll
    for (int o = 32; o; o >>= 1) M = fmaxf(M, __shfl_xor(M, o));
    float e = __expf(v - M);
#pragma unroll
    for (int o = 32; o; o >>= 1) e += __shfl_xor(e, o);
    float Z = M + __logf(e);
    float gold = 0.f;
    for (int t = j; t < len; t += 64) {
        int yt = y0[b * Tv + t];
        int yp = (t == 0) ? 2 : y0[b * Tv + t - 1];
        gold += yb[t * 64 + yt] + trans[yt * 64 + yp];
    }
#pragma unroll
    for (int o = 32; o; o >>= 1) gold += __shfl_xor(gold, o);
    if (j == 0) out[b] = Z - gold;
}

// ---------------- host ----------------
extern "C" void kernel_launch(void* const* d_in, const int* in_sizes, int n_in,
                              void* d_out, int out_size, void* d_ws, size_t ws_size,
                              hipStream_t stream) {
    const int*   x     = (const int*)d_in[0];
    const float* f     = (const float*)d_in[1];
    const int*   y0    = (const int*)d_in[2];
    const float* embed = (const float*)d_in[3];
    const float* Wih0f = (const float*)d_in[4],  *Whh0f = (const float*)d_in[5];
    const float* bih0f = (const float*)d_in[6],  *bhh0f = (const float*)d_in[7];
    const float* Wih0b = (const float*)d_in[8],  *Whh0b = (const float*)d_in[9];
    const float* bih0b = (const float*)d_in[10], *bhh0b = (const float*)d_in[11];
    const float* Wih1f = (const float*)d_in[12], *Whh1f = (const float*)d_in[13];
    const float* bih1f = (const float*)d_in[14], *bhh1f = (const float*)d_in[15];
    const float* Wih1b = (const float*)d_in[16], *Whh1b = (const float*)d_in[17];
    const float* bih1b = (const float*)d_in[18], *bhh1b = (const float*)d_in[19];
    const float* out_w = (const float*)d_in[20];
    const float* out_b = (const float*)d_in[21];
    const float* trans = (const float*)d_in[22];

    char* ws = (char*)d_ws;
    size_t off = 0;
    auto alloc = [&](size_t bytes) -> void* {
        off = (off + 255) & ~(size_t)255;
        void* p = ws + off;
        off += bytes;
        return p;
    };
    unsigned short* X0   = (unsigned short*)alloc((size_t)MROWS * K0PAD * 2);
    unsigned short* dW0  = (unsigned short*)alloc((size_t)2 * 1024 * K0PAD * 2);
    unsigned short* dW1  = (unsigned short*)alloc((size_t)2 * 1024 * 512 * 2);
    unsigned short* dOW  = (unsigned short*)alloc((size_t)64 * 512 * 2);
    unsigned short* Wfrag= (unsigned short*)alloc((size_t)4 * NSLICE * WFRAG_PER_DS * 2);
    float*          bias = (float*)alloc((size_t)4096 * 4);
    int*            lens = (int*)alloc((size_t)32 * 4);
    int*            flags= (int*)alloc((size_t)2 * 2 * 256 * FLAGSTRIDE * 4);
    unsigned int*   Hst0 = (unsigned int*)alloc((size_t)2 * 256 * 4096 * 4);
    unsigned int*   Hst1 = (unsigned int*)alloc((size_t)2 * 256 * 4096 * 4);
    float*          Gin  = (float*)alloc((size_t)2 * MROWS * GATES * 4);
    unsigned short* H0   = (unsigned short*)alloc((size_t)MROWS * 512 * 2);
    unsigned short* H1   = (unsigned short*)alloc((size_t)MROWS * 512 * 2);
    float*          Y    = (float*)alloc((size_t)MROWS * Kv * 4);
    (void)ws_size; (void)in_sizes; (void)n_in; (void)out_size;

    // prep
    conv_weights<<<dim3(2048, 1, 5), 256, 0, stream>>>(Wih0f, Wih0b, Wih1f, Wih1b, out_w,
                                                       dW0, dW1, dOW);
    whh_frag<<<dim3(1024, 1, 4), 256, 0, stream>>>(Whh0f, Whh0b, Whh1f, Whh1b, Wfrag);
    bias_sum<<<16, 256, 0, stream>>>(bih0f, bhh0f, bih0b, bhh0b,
                                     bih1f, bhh1f, bih1b, bhh1b, bias);
    calc_len<<<32, 256, 0, stream>>>(x, lens);
    zero_flags<<<256, 256, 0, stream>>>(flags);
    embed_pack<<<MROWS, 64, 0, stream>>>(x, f, embed, X0);

    // layer 0
    mfma_gemm<<<dim3(MROWS / 32, 32), 64, 0, stream>>>(X0, K0PAD, dW0, K0PAD,
                                                       bias, Gin, GATES, K0PAD);
    mfma_gemm<<<dim3(MROWS / 32, 32), 64, 0, stream>>>(X0, K0PAD, dW0 + 1024 * K0PAD, K0PAD,
                                                       bias + 1024, Gin + (size_t)MROWS * GATES,
                                                       GATES, K0PAD);
    lstm_slice<<<dim3(NSLICE, 2), 256, 0, stream>>>(Gin, Wfrag, Hst0,
                                                    (unsigned int*)H0, flags, lens);

    // layer 1
    mfma_gemm<<<dim3(MROWS / 32, 32), 64, 0, stream>>>(H0, 512, dW1, 512,
                                                       bias + 2048, Gin, GATES, 512);
    mfma_gemm<<<dim3(MROWS / 32, 32), 64, 0, stream>>>(H0, 512, dW1 + 1024 * 512, 512,
                                                       bias + 3072, Gin + (size_t)MROWS * GATES,
                                                       GATES, 512);
    lstm_slice<<<dim3(NSLICE, 2), 256, 0, stream>>>(Gin, Wfrag + (size_t)2 * NSLICE * WFRAG_PER_DS,
                                                    Hst1, (unsigned int*)H1,
                                                    flags + 2 * 256 * FLAGSTRIDE, lens);

    // emissions + CRF
    mfma_gemm<<<dim3(MROWS / 32, 2), 64, 0, stream>>>(H1, 512, dOW, 512,
                                                      out_b, Y, Kv, 512);
    crf_kernel<<<32, 64, 0, stream>>>(Y, trans, y0, lens, (float*)d_out);
}